// Round 6
// baseline (233.770 us; speedup 1.0000x reference)
//
#include <hip/hip_runtime.h>
#include <hip/hip_bf16.h>
#include <hip/hip_fp16.h>
#include <cstdint>

typedef __attribute__((ext_vector_type(4))) float f32x4;
typedef __attribute__((ext_vector_type(8))) short s16x8;

#define DEVI static __device__ __forceinline__

constexpr int Bc = 8, Tc = 2048, Sc = 8, Dc = 256;
constexpr int Mc = Bc * Tc * Sc;  // 131072 rows

// plain-cast f32->bf16 (RNE): compiler packs pairs into v_cvt_pk_bf16_f32
DEVI unsigned short f2bf(float x) {
  return __bfloat16_as_ushort(__float2bfloat16(x));
}

DEVI s16x8 cvt8(f32x4 a, f32x4 b) {
  s16x8 o;
  o[0] = (short)f2bf(a[0]); o[1] = (short)f2bf(a[1]);
  o[2] = (short)f2bf(a[2]); o[3] = (short)f2bf(a[3]);
  o[4] = (short)f2bf(b[0]); o[5] = (short)f2bf(b[1]);
  o[6] = (short)f2bf(b[2]); o[7] = (short)f2bf(b[3]);
  return o;
}

DEVI f32x4 mfma16(s16x8 a, s16x8 b, f32x4 c) {
  return __builtin_amdgcn_mfma_f32_16x16x32_bf16(a, b, c, 0, 0, 0);
}

// async global->LDS, 16B per lane (dest must be wave-uniform base + lane*16)
DEVI void gld16(const void* g, void* l) {
  __builtin_amdgcn_global_load_lds(
      (const __attribute__((address_space(1))) unsigned int*)g,
      (__attribute__((address_space(3))) unsigned int*)l, 16, 0, 0);
}

// ---------------- weight transpose+convert (both W in one kernel) ----------------
__global__ void cvtW_k(const float* __restrict__ Win, const float* __restrict__ Wout,
                       unsigned short* __restrict__ wtin, unsigned short* __restrict__ wtout) {
  int tid = blockIdx.x * blockDim.x + threadIdx.x;
  if (tid < 512 * 256) {
    int c = tid >> 8, r = tid & 255;
    wtin[tid] = f2bf(Win[r * 512 + c]);
  } else {
    int t = tid - 512 * 256;
    int c = t >> 8, r = t & 255;
    wtout[t] = f2bf(Wout[r * 256 + c]);
  }
}

// ---------------- GEMM1: h = x@W_in (x f32, converted in-kernel), fused act -> (a,b) fp16 ----------------
// Full-K A staging: As = 8 K-panels (64KB), written ONCE per block from reg-staged
// f32 loads (single drain, single barrier). K-loop holds only B's gld_lds dbuf ->
// per-iter barrier drains 2 L2-hot loads issued a full iter earlier.
// grid 4096 = 1024 mtiles x 4 ctiles (64 gate + 64 cand cols each).
__global__ __launch_bounds__(256, 2) void gemm1_k(
    const float* __restrict__ x,             // [M][256] f32
    const unsigned short* __restrict__ wt,   // [512][256] bf16 = W_in^T
    const float* __restrict__ bias,          // [512]
    __half2* __restrict__ ab)                // [M*256] (a,b) pairs
{
  __shared__ unsigned short As[8][128 * 32];  // 64KB: K-panel kk = cols [kk*32, kk*32+32)
  __shared__ unsigned short Bs[2][128 * 32];  // 16KB: rows 0..63 gate cols, 64..127 cand

  int bid = blockIdx.x;
  int swz = (bid & 7) * 512 + (bid >> 3);   // XCD-contiguous: same mtile's 4 ctiles adjacent
  int mtile = swz >> 2, ctile = swz & 3;
  int tid = threadIdx.x;
  int lane = tid & 63, wave = tid >> 6;
  int wr = wave >> 1, wc = wave & 1;

  const short* wsrc = (const short*)wt;

  // A staging: thread t covers rows {j*8 + (t>>5)}, cols [(t&31)*8, +8)
  int arow = tid >> 5;            // 0..7
  int ac0 = (tid & 31) * 8;       // 0..248
  int apanel = ac0 >> 5;          // K-panel
  int acol = ac0 & 31;
  const float* gA = x + (size_t)(mtile * 128 + arow) * 256 + ac0;

  int browB = tid >> 2, bco = (tid & 3) * 8;
  auto wrow = [&](int br) { return (br < 64) ? (ctile * 64 + br) : (192 + ctile * 64 + br); };
  auto STB = [&](int buf, int k0) {
    gld16(wsrc + (size_t)wrow(browB) * 256 + k0 + bco,      &Bs[buf][(size_t)tid * 8]);
    gld16(wsrc + (size_t)wrow(browB + 64) * 256 + k0 + bco, &Bs[buf][2048 + (size_t)tid * 8]);
  };

  // issue ALL A loads (32 x f32x4, deep queue) + first B panel
  f32x4 pa[16][2];
  #pragma unroll
  for (int j = 0; j < 16; ++j) {
    pa[j][0] = *(const f32x4*)(gA + (size_t)j * 8 * 256);
    pa[j][1] = *(const f32x4*)(gA + (size_t)j * 8 * 256 + 4);
  }
  STB(0, 0);
  // convert + write all 16 panel chunks (consumes loads in issue order)
  #pragma unroll
  for (int j = 0; j < 16; ++j) {
    int row = j * 8 + arow;
    *(s16x8*)&As[apanel][row * 32 + acol] = cvt8(pa[j][0], pa[j][1]);
  }
  __syncthreads();   // single full drain: A writes + B panel 0

  f32x4 accG[4][2] = {}; f32x4 accC[4][2] = {};

  #pragma unroll
  for (int kk = 0; kk < 8; ++kk) {
    int cur = kk & 1;
    if (kk < 7) STB(cur ^ 1, (kk + 1) * 32);
    int kg = (lane >> 4) * 8;
    s16x8 aF[4], bG[2], bC[2];
    #pragma unroll
    for (int mf = 0; mf < 4; ++mf)
      aF[mf] = *(const s16x8*)&As[kk][(wr * 64 + mf * 16 + (lane & 15)) * 32 + kg];
    #pragma unroll
    for (int nf = 0; nf < 2; ++nf) {
      bG[nf] = *(const s16x8*)&Bs[cur][(wc * 32 + nf * 16 + (lane & 15)) * 32 + kg];
      bC[nf] = *(const s16x8*)&Bs[cur][(64 + wc * 32 + nf * 16 + (lane & 15)) * 32 + kg];
    }
    #pragma unroll
    for (int mf = 0; mf < 4; ++mf)
      #pragma unroll
      for (int nf = 0; nf < 2; ++nf) {
        accG[mf][nf] = mfma16(aF[mf], bG[nf], accG[mf][nf]);
        accC[mf][nf] = mfma16(aF[mf], bC[nf], accC[mf][nf]);
      }
    if (kk < 7) __syncthreads();   // protects Bs double-buffer only
  }

  int orow0 = mtile * 128 + wr * 64 + (lane >> 4) * 4;
  #pragma unroll
  for (int nf = 0; nf < 2; ++nf) {
    int colg = ctile * 64 + wc * 32 + nf * 16 + (lane & 15);
    float bg = bias[colg], bcd = bias[colg + 256];
    #pragma unroll
    for (int mf = 0; mf < 4; ++mf) {
      #pragma unroll
      for (int r = 0; r < 4; ++r) {
        int row = orow0 + mf * 16 + r;
        float g = accG[mf][nf][r] + bg;
        float c = accC[mf][nf][r] + bcd;
        float alpha = 1.f / (1.f + __expf(-g));
        float e2 = __expf(2.f * c);
        float th = 1.f - 2.f / (e2 + 1.f);   // tanh(c), stable for +/-inf
        __half2 h;
        h.x = __float2half(1.f - alpha);
        h.y = __float2half(alpha * th);
        ab[(size_t)row * 256 + colg] = h;
      }
    }
  }
}

// ---------------- scan over T: state = a*state + b ----------------
__global__ __launch_bounds__(64) void scan_k(const unsigned int* __restrict__ ab,
                                             unsigned short* __restrict__ yb)
{
  int blk = blockIdx.x;
  int dq = blk & 3, bs = blk >> 2;             // bs: 0..63
  int d = dq * 64 + (int)threadIdx.x;
  size_t base = ((size_t)(bs >> 3) * Tc * Sc + (bs & 7)) * Dc + d;
  const size_t st = (size_t)Sc * Dc;           // 2048 elems per t-step

  unsigned q[8][8];
  auto LDG = [&](int i, int t0) {
    #pragma unroll
    for (int u = 0; u < 8; ++u)
      q[i][u] = ab[base + (size_t)(t0 + u) * st];
  };
  #pragma unroll
  for (int i = 0; i < 8; ++i) LDG(i, i * 8);

  float stt = 0.f;
  for (int t0 = 0; t0 < Tc; t0 += 64) {
    #pragma unroll
    for (int i = 0; i < 8; ++i) {
      #pragma unroll
      for (int u = 0; u < 8; ++u) {
        unsigned v = q[i][u];
        float av = __half2float(__ushort_as_half((unsigned short)(v & 0xffffu)));
        float bv = __half2float(__ushort_as_half((unsigned short)(v >> 16)));
        stt = fmaf(av, stt, bv);
        yb[base + (size_t)(t0 + i * 8 + u) * st] = f2bf(stt);
      }
      if (t0 + 64 < Tc) LDG(i, t0 + 64 + i * 8);
    }
  }
}

// ---------------- GEMM2: out = y@W_out + b_out ----------------
__global__ __launch_bounds__(256, 2) void gemm2_k(
    const unsigned short* __restrict__ yb,   // [M][256] bf16
    const unsigned short* __restrict__ wt,   // [256][256] bf16 = W_out^T
    const float* __restrict__ bias,          // [256]
    float* __restrict__ out)
{
  __shared__ unsigned short As[2][128 * 32];
  __shared__ unsigned short Bs[2][128 * 32];

  int bid = blockIdx.x;
  int swz = (bid & 7) * 256 + (bid >> 3);
  int mtile = swz >> 1, ctile = swz & 1;
  int tid = threadIdx.x;
  int lane = tid & 63, wave = tid >> 6;
  int wr = wave >> 1, wc = wave & 1;

  const short* ys = (const short*)yb;
  const short* wsrc = (const short*)wt;

  int srow = tid >> 2, sch = (tid & 3) * 8;
  size_t gArow = (size_t)(mtile * 128 + srow) * 256;
  size_t gBrow = (size_t)(ctile * 128 + srow) * 256;

  auto STAGE = [&](int buf, int k0) {
    gld16(ys + gArow + k0 + sch,                    &As[buf][(size_t)tid * 8]);
    gld16(ys + gArow + (size_t)64 * 256 + k0 + sch, &As[buf][2048 + (size_t)tid * 8]);
    gld16(wsrc + gBrow + k0 + sch,                    &Bs[buf][(size_t)tid * 8]);
    gld16(wsrc + gBrow + (size_t)64 * 256 + k0 + sch, &Bs[buf][2048 + (size_t)tid * 8]);
  };

  f32x4 acc[4][4] = {};

  STAGE(0, 0);
  __syncthreads();
  #pragma unroll
  for (int kk = 0; kk < 8; ++kk) {
    int cur = kk & 1;
    if (kk < 7) STAGE(cur ^ 1, (kk + 1) * 32);
    int kg = (lane >> 4) * 8;
    s16x8 aF[4], bF[4];
    #pragma unroll
    for (int mf = 0; mf < 4; ++mf)
      aF[mf] = *(const s16x8*)&As[cur][(wr * 64 + mf * 16 + (lane & 15)) * 32 + kg];
    #pragma unroll
    for (int nf = 0; nf < 4; ++nf)
      bF[nf] = *(const s16x8*)&Bs[cur][(wc * 64 + nf * 16 + (lane & 15)) * 32 + kg];
    #pragma unroll
    for (int mf = 0; mf < 4; ++mf)
      #pragma unroll
      for (int nf = 0; nf < 4; ++nf)
        acc[mf][nf] = mfma16(aF[mf], bF[nf], acc[mf][nf]);
    __syncthreads();
  }

  int orow0 = mtile * 128 + wr * 64 + (lane >> 4) * 4;
  #pragma unroll
  for (int nf = 0; nf < 4; ++nf) {
    int col = ctile * 128 + wc * 64 + nf * 16 + (lane & 15);
    float bo = bias[col];
    #pragma unroll
    for (int mf = 0; mf < 4; ++mf) {
      #pragma unroll
      for (int r = 0; r < 4; ++r) {
        int row = orow0 + mf * 16 + r;
        out[(size_t)row * 256 + col] = acc[mf][nf][r] + bo;
      }
    }
  }
}

// ---------------- host ----------------
extern "C" void kernel_launch(void* const* d_in, const int* in_sizes, int n_in,
                              void* d_out, int out_size, void* d_ws, size_t ws_size,
                              hipStream_t stream)
{
  const float* x    = (const float*)d_in[0];
  const float* Win  = (const float*)d_in[1];
  const float* bin  = (const float*)d_in[2];
  const float* Wout = (const float*)d_in[3];
  const float* bout = (const float*)d_in[4];
  float* out = (float*)d_out;
  char* ws = (char*)d_ws;

  // ws layout: Wt_in (256 KiB) | Wt_out (128 KiB) | yb (64 MiB) | ab (128 MiB, if it fits)
  unsigned short* wtin  = (unsigned short*)(ws);
  unsigned short* wtout = (unsigned short*)(ws + 262144);
  unsigned short* yb    = (unsigned short*)(ws + 393216);
  size_t abOff = 393216 + (size_t)Mc * 256 * 2;
  size_t needFull = abOff + (size_t)Mc * 256 * 4;
  // fallback: stage (a,b) pairs in d_out (dead until gemm2 overwrites it)
  __half2* ab = (ws_size >= needFull) ? (__half2*)(ws + abOff) : (__half2*)d_out;

  cvtW_k<<<768, 256, 0, stream>>>(Win, Wout, wtin, wtout);
  gemm1_k<<<4096, 256, 0, stream>>>(x, wtin, bin, ab);
  scan_k<<<256, 64, 0, stream>>>((const unsigned int*)ab, yb);
  gemm2_k<<<2048, 256, 0, stream>>>(yb, wtout, bout, out);
}

// Round 7
// 207.482 us; speedup vs baseline: 1.1267x; 1.1267x over previous
//
#include <hip/hip_runtime.h>
#include <hip/hip_bf16.h>
#include <hip/hip_fp16.h>
#include <cstdint>

typedef __attribute__((ext_vector_type(4))) float f32x4;
typedef __attribute__((ext_vector_type(8))) short s16x8;

#define DEVI static __device__ __forceinline__

constexpr int Bc = 8, Tc = 2048, Sc = 8, Dc = 256;
constexpr int Mc = Bc * Tc * Sc;  // 131072 rows

// plain-cast f32->bf16 (RNE): compiler packs pairs into v_cvt_pk_bf16_f32
DEVI unsigned short f2bf(float x) {
  return __bfloat16_as_ushort(__float2bfloat16(x));
}

DEVI f32x4 mfma16(s16x8 a, s16x8 b, f32x4 c) {
  return __builtin_amdgcn_mfma_f32_16x16x32_bf16(a, b, c, 0, 0, 0);
}

// async global->LDS, 16B per lane (dest must be wave-uniform base + lane*16)
DEVI void gld16(const void* g, void* l) {
  __builtin_amdgcn_global_load_lds(
      (const __attribute__((address_space(1))) unsigned int*)g,
      (__attribute__((address_space(3))) unsigned int*)l, 16, 0, 0);
}

// ---------------- x f32 -> bf16 ----------------
__global__ void cvt_x_k(const float* __restrict__ in, unsigned short* __restrict__ out, int n) {
  int i = (blockIdx.x * blockDim.x + threadIdx.x) * 8;
  int stride = gridDim.x * blockDim.x * 8;
  for (; i < n; i += stride) {
    f32x4 a = *(const f32x4*)(in + i);
    f32x4 b = *(const f32x4*)(in + i + 4);
    s16x8 o;
    o[0] = (short)f2bf(a[0]); o[1] = (short)f2bf(a[1]);
    o[2] = (short)f2bf(a[2]); o[3] = (short)f2bf(a[3]);
    o[4] = (short)f2bf(b[0]); o[5] = (short)f2bf(b[1]);
    o[6] = (short)f2bf(b[2]); o[7] = (short)f2bf(b[3]);
    *(s16x8*)(out + i) = o;
  }
}

// ---------------- weight transpose+convert (both W in one kernel) ----------------
__global__ void cvtW_k(const float* __restrict__ Win, const float* __restrict__ Wout,
                       unsigned short* __restrict__ wtin, unsigned short* __restrict__ wtout) {
  int tid = blockIdx.x * blockDim.x + threadIdx.x;
  if (tid < 512 * 256) {
    int c = tid >> 8, r = tid & 255;
    wtin[tid] = f2bf(Win[r * 512 + c]);
  } else {
    int t = tid - 512 * 256;
    int c = t >> 8, r = t & 255;
    wtout[t] = f2bf(Wout[r * 256 + c]);
  }
}

// ---------------- GEMM1: h = x@W_in, fused sigmoid/tanh -> (a,b) fp16 pairs ----------------
// r2 structure (all staging via global_load_lds) + BK=64 as two [128][32] sub-panels
// (64B row stride keeps ds_read_b128 at the free <=8-way aliasing). 4 K-iters.
// grid 4096 = 1024 mtiles x 4 ctiles (64 gate + 64 cand cols each).
__global__ __launch_bounds__(256, 2) void gemm1_k(
    const unsigned short* __restrict__ xb,   // [M][256] bf16
    const unsigned short* __restrict__ wt,   // [512][256] bf16 = W_in^T
    const float* __restrict__ bias,          // [512]
    __half2* __restrict__ ab)                // [M*256] (a,b) pairs
{
  __shared__ unsigned short As[2][2][128 * 32];  // [buf][k-subpanel][row*32+k]
  __shared__ unsigned short Bs[2][2][128 * 32];  // rows 0..63 gate, 64..127 cand

  int bid = blockIdx.x;
  int swz = (bid & 7) * 512 + (bid >> 3);   // XCD-contiguous: same mtile's 4 ctiles adjacent
  int mtile = swz >> 2, ctile = swz & 3;
  int tid = threadIdx.x;
  int lane = tid & 63, wave = tid >> 6;
  int wr = wave >> 1, wc = wave & 1;

  const short* xs = (const short*)xb;
  const short* wsrc = (const short*)wt;

  // staging: chunk j = q*256+tid (16B each); p = j>>9 (sub-panel), r = (j>>2)&127, cc = j&3
  auto STAGE = [&](int buf, int k0) {
    unsigned short* Ad = &As[buf][0][0];
    unsigned short* Bd = &Bs[buf][0][0];
    #pragma unroll
    for (int q = 0; q < 4; ++q) {
      int j = q * 256 + tid;
      int p = j >> 9, r = (j >> 2) & 127, cc = j & 3;
      int koff = k0 + p * 32 + cc * 8;
      gld16(xs + (size_t)(mtile * 128 + r) * 256 + koff, Ad + (size_t)j * 8);
      int wrow = (r < 64) ? (ctile * 64 + r) : (192 + ctile * 64 + r);
      gld16(wsrc + (size_t)wrow * 256 + koff, Bd + (size_t)j * 8);
    }
  };

  f32x4 accG[4][2] = {}; f32x4 accC[4][2] = {};

  STAGE(0, 0);
  __syncthreads();
  #pragma unroll
  for (int kk = 0; kk < 4; ++kk) {
    int cur = kk & 1;
    if (kk < 3) STAGE(cur ^ 1, (kk + 1) * 64);
    int kg = (lane >> 4) * 8;
    #pragma unroll
    for (int ks = 0; ks < 2; ++ks) {
      s16x8 aF[4], bG[2], bC[2];
      #pragma unroll
      for (int mf = 0; mf < 4; ++mf)
        aF[mf] = *(const s16x8*)&As[cur][ks][(wr * 64 + mf * 16 + (lane & 15)) * 32 + kg];
      #pragma unroll
      for (int nf = 0; nf < 2; ++nf) {
        bG[nf] = *(const s16x8*)&Bs[cur][ks][(wc * 32 + nf * 16 + (lane & 15)) * 32 + kg];
        bC[nf] = *(const s16x8*)&Bs[cur][ks][(64 + wc * 32 + nf * 16 + (lane & 15)) * 32 + kg];
      }
      #pragma unroll
      for (int mf = 0; mf < 4; ++mf)
        #pragma unroll
        for (int nf = 0; nf < 2; ++nf) {
          accG[mf][nf] = mfma16(aF[mf], bG[nf], accG[mf][nf]);
          accC[mf][nf] = mfma16(aF[mf], bC[nf], accC[mf][nf]);
        }
    }
    if (kk < 3) __syncthreads();
  }

  int orow0 = mtile * 128 + wr * 64 + (lane >> 4) * 4;
  #pragma unroll
  for (int nf = 0; nf < 2; ++nf) {
    int colg = ctile * 64 + wc * 32 + nf * 16 + (lane & 15);
    float bg = bias[colg], bcd = bias[colg + 256];
    #pragma unroll
    for (int mf = 0; mf < 4; ++mf) {
      #pragma unroll
      for (int r = 0; r < 4; ++r) {
        int row = orow0 + mf * 16 + r;
        float g = accG[mf][nf][r] + bg;
        float c = accC[mf][nf][r] + bcd;
        float alpha = 1.f / (1.f + __expf(-g));
        float e2 = __expf(2.f * c);
        float th = 1.f - 2.f / (e2 + 1.f);   // tanh(c), stable for +/-inf
        __half2 h;
        h.x = __float2half(1.f - alpha);
        h.y = __float2half(alpha * th);
        ab[(size_t)row * 256 + colg] = h;
      }
    }
  }
}

// ---------------- scan over T: state = a*state + b ----------------
// grid 256 blocks x 64 lanes; depth-8 x 8 register prefetch ring.
__global__ __launch_bounds__(64) void scan_k(const unsigned int* __restrict__ ab,
                                             unsigned short* __restrict__ yb)
{
  int blk = blockIdx.x;
  int dq = blk & 3, bs = blk >> 2;             // bs: 0..63
  int d = dq * 64 + (int)threadIdx.x;
  size_t base = ((size_t)(bs >> 3) * Tc * Sc + (bs & 7)) * Dc + d;
  const size_t st = (size_t)Sc * Dc;           // 2048 elems per t-step

  unsigned q[8][8];
  auto LDG = [&](int i, int t0) {
    #pragma unroll
    for (int u = 0; u < 8; ++u)
      q[i][u] = ab[base + (size_t)(t0 + u) * st];
  };
  #pragma unroll
  for (int i = 0; i < 8; ++i) LDG(i, i * 8);

  float stt = 0.f;
  for (int t0 = 0; t0 < Tc; t0 += 64) {
    #pragma unroll
    for (int i = 0; i < 8; ++i) {
      #pragma unroll
      for (int u = 0; u < 8; ++u) {
        unsigned v = q[i][u];
        float av = __half2float(__ushort_as_half((unsigned short)(v & 0xffffu)));
        float bv = __half2float(__ushort_as_half((unsigned short)(v >> 16)));
        stt = fmaf(av, stt, bv);
        yb[base + (size_t)(t0 + i * 8 + u) * st] = f2bf(stt);
      }
      if (t0 + 64 < Tc) LDG(i, t0 + 64 + i * 8);
    }
  }
}

// ---------------- GEMM2: out = y@W_out + b_out ----------------
// Same BK=64 sub-panel structure. grid 2048 = 1024 mtiles x 2 ctiles.
__global__ __launch_bounds__(256, 2) void gemm2_k(
    const unsigned short* __restrict__ yb,   // [M][256] bf16
    const unsigned short* __restrict__ wt,   // [256][256] bf16 = W_out^T
    const float* __restrict__ bias,          // [256]
    float* __restrict__ out)
{
  __shared__ unsigned short As[2][2][128 * 32];
  __shared__ unsigned short Bs[2][2][128 * 32];

  int bid = blockIdx.x;
  int swz = (bid & 7) * 256 + (bid >> 3);
  int mtile = swz >> 1, ctile = swz & 1;
  int tid = threadIdx.x;
  int lane = tid & 63, wave = tid >> 6;
  int wr = wave >> 1, wc = wave & 1;

  const short* ys = (const short*)yb;
  const short* wsrc = (const short*)wt;

  auto STAGE = [&](int buf, int k0) {
    unsigned short* Ad = &As[buf][0][0];
    unsigned short* Bd = &Bs[buf][0][0];
    #pragma unroll
    for (int q = 0; q < 4; ++q) {
      int j = q * 256 + tid;
      int p = j >> 9, r = (j >> 2) & 127, cc = j & 3;
      int koff = k0 + p * 32 + cc * 8;
      gld16(ys + (size_t)(mtile * 128 + r) * 256 + koff, Ad + (size_t)j * 8);
      gld16(wsrc + (size_t)(ctile * 128 + r) * 256 + koff, Bd + (size_t)j * 8);
    }
  };

  f32x4 acc[4][4] = {};

  STAGE(0, 0);
  __syncthreads();
  #pragma unroll
  for (int kk = 0; kk < 4; ++kk) {
    int cur = kk & 1;
    if (kk < 3) STAGE(cur ^ 1, (kk + 1) * 64);
    int kg = (lane >> 4) * 8;
    #pragma unroll
    for (int ks = 0; ks < 2; ++ks) {
      s16x8 aF[4], bF[4];
      #pragma unroll
      for (int mf = 0; mf < 4; ++mf)
        aF[mf] = *(const s16x8*)&As[cur][ks][(wr * 64 + mf * 16 + (lane & 15)) * 32 + kg];
      #pragma unroll
      for (int nf = 0; nf < 4; ++nf)
        bF[nf] = *(const s16x8*)&Bs[cur][ks][(wc * 64 + nf * 16 + (lane & 15)) * 32 + kg];
      #pragma unroll
      for (int mf = 0; mf < 4; ++mf)
        #pragma unroll
        for (int nf = 0; nf < 4; ++nf)
          acc[mf][nf] = mfma16(aF[mf], bF[nf], acc[mf][nf]);
    }
    if (kk < 3) __syncthreads();
  }

  int orow0 = mtile * 128 + wr * 64 + (lane >> 4) * 4;
  #pragma unroll
  for (int nf = 0; nf < 4; ++nf) {
    int col = ctile * 128 + wc * 64 + nf * 16 + (lane & 15);
    float bo = bias[col];
    #pragma unroll
    for (int mf = 0; mf < 4; ++mf) {
      #pragma unroll
      for (int r = 0; r < 4; ++r) {
        int row = orow0 + mf * 16 + r;
        out[(size_t)row * 256 + col] = acc[mf][nf][r] + bo;
      }
    }
  }
}

// ---------------- host ----------------
extern "C" void kernel_launch(void* const* d_in, const int* in_sizes, int n_in,
                              void* d_out, int out_size, void* d_ws, size_t ws_size,
                              hipStream_t stream)
{
  const float* x    = (const float*)d_in[0];
  const float* Win  = (const float*)d_in[1];
  const float* bin  = (const float*)d_in[2];
  const float* Wout = (const float*)d_in[3];
  const float* bout = (const float*)d_in[4];
  float* out = (float*)d_out;
  char* ws = (char*)d_ws;

  // ws layout: Wt_in (256 KiB) | Wt_out (128 KiB) | xb/yb (64 MiB) | ab (128 MiB, if it fits)
  unsigned short* wtin  = (unsigned short*)(ws);
  unsigned short* wtout = (unsigned short*)(ws + 262144);
  unsigned short* xb    = (unsigned short*)(ws + 393216);      // reused as yb after gemm1
  size_t abOff = 393216 + (size_t)Mc * 256 * 2;
  size_t needFull = abOff + (size_t)Mc * 256 * 4;
  // fallback: stage (a,b) pairs in d_out (dead until gemm2 overwrites it)
  __half2* ab = (ws_size >= needFull) ? (__half2*)(ws + abOff) : (__half2*)d_out;

  cvt_x_k<<<1024, 256, 0, stream>>>(x, xb, Mc * 256);
  cvtW_k<<<768, 256, 0, stream>>>(Win, Wout, wtin, wtout);
  gemm1_k<<<4096, 256, 0, stream>>>(xb, wtin, bin, ab);
  scan_k<<<256, 64, 0, stream>>>((const unsigned int*)ab, xb);
  gemm2_k<<<2048, 256, 0, stream>>>(xb, wtout, bout, out);
}

// Round 8
// 186.904 us; speedup vs baseline: 1.2507x; 1.1101x over previous
//
#include <hip/hip_runtime.h>
#include <hip/hip_bf16.h>
#include <hip/hip_fp16.h>
#include <cstdint>

typedef __attribute__((ext_vector_type(4))) float f32x4;
typedef __attribute__((ext_vector_type(8))) short s16x8;

#define DEVI static __device__ __forceinline__

constexpr int Bc = 8, Tc = 2048, Sc = 8, Dc = 256;
constexpr int Mc = Bc * Tc * Sc;  // 131072 rows

// plain-cast f32->bf16 (RNE): compiler packs pairs into v_cvt_pk_bf16_f32
DEVI unsigned short f2bf(float x) {
  return __bfloat16_as_ushort(__float2bfloat16(x));
}

DEVI f32x4 mfma16(s16x8 a, s16x8 b, f32x4 c) {
  return __builtin_amdgcn_mfma_f32_16x16x32_bf16(a, b, c, 0, 0, 0);
}

// async global->LDS, 16B per lane (dest must be wave-uniform base + lane*16)
DEVI void gld16(const void* g, void* l) {
  __builtin_amdgcn_global_load_lds(
      (const __attribute__((address_space(1))) unsigned int*)g,
      (__attribute__((address_space(3))) unsigned int*)l, 16, 0, 0);
}

// ---------------- x f32 -> bf16 ----------------
__global__ void cvt_x_k(const float* __restrict__ in, unsigned short* __restrict__ out, int n) {
  int i = (blockIdx.x * blockDim.x + threadIdx.x) * 8;
  int stride = gridDim.x * blockDim.x * 8;
  for (; i < n; i += stride) {
    f32x4 a = *(const f32x4*)(in + i);
    f32x4 b = *(const f32x4*)(in + i + 4);
    s16x8 o;
    o[0] = (short)f2bf(a[0]); o[1] = (short)f2bf(a[1]);
    o[2] = (short)f2bf(a[2]); o[3] = (short)f2bf(a[3]);
    o[4] = (short)f2bf(b[0]); o[5] = (short)f2bf(b[1]);
    o[6] = (short)f2bf(b[2]); o[7] = (short)f2bf(b[3]);
    *(s16x8*)(out + i) = o;
  }
}

// ---------------- weight transpose+convert (both W in one kernel) ----------------
__global__ void cvtW_k(const float* __restrict__ Win, const float* __restrict__ Wout,
                       unsigned short* __restrict__ wtin, unsigned short* __restrict__ wtout) {
  int tid = blockIdx.x * blockDim.x + threadIdx.x;
  if (tid < 512 * 256) {
    int c = tid >> 8, r = tid & 255;
    wtin[tid] = f2bf(Win[r * 512 + c]);
  } else {
    int t = tid - 512 * 256;
    int c = t >> 8, r = t & 255;
    wtout[t] = f2bf(Wout[r * 256 + c]);
  }
}

// ---------------- fused GEMM1 + activation + scan ----------------
// Block = (b, s, dq): 256 blocks x 512 threads (8 waves). W_in rows for this dq
// (64 gate + 64 cand) resident in LDS for the whole kernel (panelized [128][32]x8).
// x streams as dbuf 64-row chunks; wave w (rg=w>>2, cg=w&3) computes rows
// rg*32+[0,32) x cols cg*16+[0,16) for gate AND cand -> act in-reg -> abuf half2.
// Wave0 scans 64 t-steps per chunk (state in regs across chunks), writes y bf16.
__global__ __launch_bounds__(512, 1) void g1scan_k(
    const unsigned short* __restrict__ xb,   // [M][256] bf16
    const unsigned short* __restrict__ wt,   // [512][256] bf16 = W_in^T
    const float* __restrict__ bias,          // [512]
    unsigned short* __restrict__ yb)         // [M][256] bf16
{
  __shared__ unsigned short As[2][8 * 64 * 32];   // 2 x 32 KB, panel p = K [p*32,+32)
  __shared__ unsigned short Ws[8 * 128 * 32];     // 64 KB, rows 0..63 gate, 64..127 cand
  __shared__ unsigned int   abuf[64 * 64];        // 16 KB: [t_local][d_local] (a,b) half2

  int bid = blockIdx.x;
  int b = bid >> 5, s = (bid >> 2) & 7, dq = bid & 3;
  int tid = threadIdx.x;
  int lane = tid & 63, wave = tid >> 6;
  int rg = wave >> 2, cg = wave & 3;

  const short* xs = (const short*)xb;
  const short* wsrc = (const short*)wt;
  size_t rowbase = (size_t)b * 16384 + s;   // global row = rowbase + t*8

  // stage W once: 4096 16B chunks; j -> panel j>>9, row (j>>2)&127, 16B sub (j&3)
  #pragma unroll
  for (int q = 0; q < 8; ++q) {
    int j = q * 512 + tid;
    int p = j >> 9, rem = j & 511, r = rem >> 2, cc = rem & 3;
    int wrow = (r < 64) ? (dq * 64 + r) : (256 + dq * 64 + (r - 64));
    gld16(wsrc + (size_t)wrow * 256 + p * 32 + cc * 8,
          (unsigned short*)Ws + (size_t)j * 8);
  }

  auto STAGE_A = [&](int buf, int t0) {
    #pragma unroll
    for (int q = 0; q < 4; ++q) {
      int j = q * 512 + tid;
      int p = j >> 8, rem = j & 255, r = rem >> 2, cc = rem & 3;
      size_t grow = rowbase + (size_t)(t0 + r) * 8;
      gld16(xs + grow * 256 + p * 32 + cc * 8,
            (unsigned short*)As + (size_t)buf * 16384 + (size_t)j * 8);
    }
  };

  STAGE_A(0, 0);

  int cl = cg * 16 + (lane & 15);          // d-local col for this thread
  float bg = bias[dq * 64 + cl];
  float bc = bias[256 + dq * 64 + cl];
  int kg = (lane >> 4) * 8;

  float stt = 0.f;                          // scan state (wave0 lanes, d = lane)

  __syncthreads();

  for (int ch = 0; ch < 32; ++ch) {
    int cur = ch & 1;
    if (ch < 31) STAGE_A(cur ^ 1, (ch + 1) * 64);

    f32x4 accG[2] = {}, accC[2] = {};
    #pragma unroll
    for (int kf = 0; kf < 8; ++kf) {
      s16x8 aF[2], bG, bC;
      #pragma unroll
      for (int mf = 0; mf < 2; ++mf)
        aF[mf] = *(const s16x8*)((unsigned short*)As + (size_t)cur * 16384 + kf * 2048 +
                                 (rg * 32 + mf * 16 + (lane & 15)) * 32 + kg);
      bG = *(const s16x8*)((unsigned short*)Ws + kf * 4096 + cl * 32 + kg);
      bC = *(const s16x8*)((unsigned short*)Ws + kf * 4096 + (64 + cl) * 32 + kg);
      #pragma unroll
      for (int mf = 0; mf < 2; ++mf) {
        accG[mf] = mfma16(aF[mf], bG, accG[mf]);
        accC[mf] = mfma16(aF[mf], bC, accC[mf]);
      }
    }

    // activation in-register (gate & cand of same (row,col) live in same thread)
    unsigned pk[2][4];
    #pragma unroll
    for (int mf = 0; mf < 2; ++mf)
      #pragma unroll
      for (int r = 0; r < 4; ++r) {
        float g = accG[mf][r] + bg;
        float c = accC[mf][r] + bc;
        float alpha = 1.f / (1.f + __expf(-g));
        float e2 = __expf(2.f * c);
        float th = 1.f - 2.f / (e2 + 1.f);   // tanh(c), stable for +/-inf
        __half2 h;
        h.x = __float2half(1.f - alpha);
        h.y = __float2half(alpha * th);
        pk[mf][r] = *(unsigned*)&h;
      }

    __syncthreads();   // wave0 finished scanning abuf (prev chunk)

    #pragma unroll
    for (int mf = 0; mf < 2; ++mf)
      #pragma unroll
      for (int r = 0; r < 4; ++r) {
        int row = rg * 32 + mf * 16 + (lane >> 4) * 4 + r;
        abuf[row * 64 + cl] = pk[mf][r];
      }

    __syncthreads();   // abuf ready

    if (wave == 0) {
      size_t ybase = (rowbase + (size_t)ch * 64 * 8) * 256 + dq * 64 + lane;
      #pragma unroll
      for (int j0 = 0; j0 < 64; j0 += 16) {
        unsigned uu[16];
        #pragma unroll
        for (int u = 0; u < 16; ++u) uu[u] = abuf[(j0 + u) * 64 + lane];
        #pragma unroll
        for (int u = 0; u < 16; ++u) {
          __half2 h = *(__half2*)&uu[u];
          stt = fmaf(__half2float(h.x), stt, __half2float(h.y));
          yb[ybase + (size_t)(j0 + u) * 8 * 256] = f2bf(stt);
        }
      }
    }
  }
}

// ---------------- GEMM2: out = y@W_out + b_out ----------------
// BK=64 as two [128][32] sub-panels. grid 2048 = 1024 mtiles x 2 ctiles.
__global__ __launch_bounds__(256, 2) void gemm2_k(
    const unsigned short* __restrict__ yb,   // [M][256] bf16
    const unsigned short* __restrict__ wt,   // [256][256] bf16 = W_out^T
    const float* __restrict__ bias,          // [256]
    float* __restrict__ out)
{
  __shared__ unsigned short As[2][2][128 * 32];
  __shared__ unsigned short Bs[2][2][128 * 32];

  int bid = blockIdx.x;
  int swz = (bid & 7) * 256 + (bid >> 3);
  int mtile = swz >> 1, ctile = swz & 1;
  int tid = threadIdx.x;
  int lane = tid & 63, wave = tid >> 6;
  int wr = wave >> 1, wc = wave & 1;

  const short* ys = (const short*)yb;
  const short* wsrc = (const short*)wt;

  auto STAGE = [&](int buf, int k0) {
    unsigned short* Ad = &As[buf][0][0];
    unsigned short* Bd = &Bs[buf][0][0];
    #pragma unroll
    for (int q = 0; q < 4; ++q) {
      int j = q * 256 + tid;
      int p = j >> 9, r = (j >> 2) & 127, cc = j & 3;
      int koff = k0 + p * 32 + cc * 8;
      gld16(ys + (size_t)(mtile * 128 + r) * 256 + koff, Ad + (size_t)j * 8);
      gld16(wsrc + (size_t)(ctile * 128 + r) * 256 + koff, Bd + (size_t)j * 8);
    }
  };

  f32x4 acc[4][4] = {};

  STAGE(0, 0);
  __syncthreads();
  #pragma unroll
  for (int kk = 0; kk < 4; ++kk) {
    int cur = kk & 1;
    if (kk < 3) STAGE(cur ^ 1, (kk + 1) * 64);
    int kg = (lane >> 4) * 8;
    #pragma unroll
    for (int ks = 0; ks < 2; ++ks) {
      s16x8 aF[4], bF[4];
      #pragma unroll
      for (int mf = 0; mf < 4; ++mf)
        aF[mf] = *(const s16x8*)&As[cur][ks][(wr * 64 + mf * 16 + (lane & 15)) * 32 + kg];
      #pragma unroll
      for (int nf = 0; nf < 4; ++nf)
        bF[nf] = *(const s16x8*)&Bs[cur][ks][(wc * 64 + nf * 16 + (lane & 15)) * 32 + kg];
      #pragma unroll
      for (int mf = 0; mf < 4; ++mf)
        #pragma unroll
        for (int nf = 0; nf < 4; ++nf)
          acc[mf][nf] = mfma16(aF[mf], bF[nf], acc[mf][nf]);
    }
    if (kk < 3) __syncthreads();
  }

  int orow0 = mtile * 128 + wr * 64 + (lane >> 4) * 4;
  #pragma unroll
  for (int nf = 0; nf < 4; ++nf) {
    int col = ctile * 128 + wc * 64 + nf * 16 + (lane & 15);
    float bo = bias[col];
    #pragma unroll
    for (int mf = 0; mf < 4; ++mf) {
      #pragma unroll
      for (int r = 0; r < 4; ++r) {
        int row = orow0 + mf * 16 + r;
        out[(size_t)row * 256 + col] = acc[mf][nf][r] + bo;
      }
    }
  }
}

// ---------------- host ----------------
extern "C" void kernel_launch(void* const* d_in, const int* in_sizes, int n_in,
                              void* d_out, int out_size, void* d_ws, size_t ws_size,
                              hipStream_t stream)
{
  const float* x    = (const float*)d_in[0];
  const float* Win  = (const float*)d_in[1];
  const float* bin  = (const float*)d_in[2];
  const float* Wout = (const float*)d_in[3];
  const float* bout = (const float*)d_in[4];
  float* out = (float*)d_out;
  char* ws = (char*)d_ws;

  // ws layout: Wt_in (256 KiB) | Wt_out (128 KiB) | yb (64 MiB) | xb (64 MiB)
  unsigned short* wtin  = (unsigned short*)(ws);
  unsigned short* wtout = (unsigned short*)(ws + 262144);
  unsigned short* yb    = (unsigned short*)(ws + 393216);
  unsigned short* xb    = (unsigned short*)(ws + 393216 + (size_t)Mc * 256 * 2);

  cvt_x_k<<<1024, 256, 0, stream>>>(x, xb, Mc * 256);
  cvtW_k<<<768, 256, 0, stream>>>(Win, Wout, wtin, wtout);
  g1scan_k<<<256, 512, 0, stream>>>(xb, wtin, bin, yb);
  gemm2_k<<<2048, 256, 0, stream>>>(yb, wtout, bout, out);
}